// Round 3
// baseline (1170.452 us; speedup 1.0000x reference)
//
#include <hip/hip_runtime.h>
#include <math.h>

// ---------------------------------------------------------------------------
// GaussianQuant — MFMA-filtered argmax.
// score[n,k] = sum_d p*c + q*c^2;  u=[p,q] (64), v=[c,c^2] (64), score=u.v
// fp16 hi/lo split (lo pre-scaled x2048), 6 MFMAs per 16-col tile:
//   score ~= uh.vh + (ul'.vh + uh.vl') / 2048
// Sound filter: per (row, col%16, ksplit) slice keep top1+top2; flag if
// a2 >= a1 - 2B (B = rigorous per-row error bound). Exact fp32 rescore of
// winners + flagged slices reproduces the R2 expression bit-exactly.
// ---------------------------------------------------------------------------

typedef _Float16 half8 __attribute__((ext_vector_type(8)));
typedef float f32x4 __attribute__((ext_vector_type(4)));

#define DIM 32
#define NTOK 2048
#define NROWS 16384
#define KSIZE 16384
#define NSPLIT 4
#define SPLITK (KSIZE / NSPLIT)        // 4096
#define NTILES (SPLITK / 16)           // 256

// ws layout (bytes)
#define WS_M1   0                       // 32 float  (memset to 0)
#define WS_M2   128                     // 32 float
#define WS_PART 512                     // 256 double
#define WS_P    4096                    // 2 MB float
#define WS_Q    (WS_P + 2097152)        // 2 MB float
#define WS_BN   (WS_Q + 2097152)        // 64 KB float
#define WS_AH   (WS_BN + 65536)         // 2 MB fp16
#define WS_AL   (WS_AH + 2097152)       // 2 MB fp16
#define WS_BH   (WS_AL + 2097152)       // 2 MB fp16
#define WS_BL   (WS_BH + 2097152)       // 2 MB fp16
#define WS_W1   (WS_BL + 2097152)       // 4 MB float
#define WS_I1   (WS_W1 + 4194304)       // 4 MB uint
#define WS_IDX  (WS_I1 + 4194304)       // 64 KB int

__global__ __launch_bounds__(256) void kl_kernel(const float* __restrict__ z,
                                                 double* __restrict__ partials) {
  const int tid = threadIdx.x;
  const int lane = tid & 63;
  const int wave = tid >> 6;
  double s = 0.0;
  for (int j = blockIdx.x * 256 + tid; j < NTOK * 256; j += 256 * 256) {
    const int t = j >> 8, r = j & 255;
    float mu = z[t * 512 + r];
    float lv = z[t * 512 + 256 + r];
    lv = fminf(fmaxf(lv, -30.0f), 20.0f);
    float var = expf(lv);
    s += (double)(mu * mu + var - 1.0f - lv);
  }
  for (int off = 32; off > 0; off >>= 1) s += __shfl_down(s, off);
  __shared__ double wsum[4];
  if (lane == 0) wsum[wave] = s;
  __syncthreads();
  if (tid == 0) partials[blockIdx.x] = (wsum[0] + wsum[1]) + (wsum[2] + wsum[3]);
}

__global__ __launch_bounds__(256) void cbprep_kernel(const float* __restrict__ cb,
                                                     _Float16* __restrict__ Bh,
                                                     _Float16* __restrict__ Bl,
                                                     float* __restrict__ M1,
                                                     float* __restrict__ M2) {
  __shared__ unsigned lm1[DIM], lm2[DIM];
  if (threadIdx.x < DIM) { lm1[threadIdx.x] = 0u; lm2[threadIdx.x] = 0u; }
  __syncthreads();
  const int k = blockIdx.x * 256 + threadIdx.x;
  _Float16 bh[64], bl[64];
#pragma unroll
  for (int d = 0; d < DIM; ++d) {
    float c = cb[k * DIM + d];
    float c2 = c * c;
    _Float16 ch = (_Float16)c;
    _Float16 cl = (_Float16)((c - (float)ch) * 2048.0f);
    _Float16 sh = (_Float16)c2;
    _Float16 sl = (_Float16)((c2 - (float)sh) * 2048.0f);
    bh[d] = ch; bh[32 + d] = sh;
    bl[d] = cl; bl[32 + d] = sl;
    atomicMax(&lm1[d], __float_as_uint(fabsf(c)));
    atomicMax(&lm2[d], __float_as_uint(c2));
  }
#pragma unroll
  for (int i = 0; i < 8; ++i) {
    half8 vh, vl;
#pragma unroll
    for (int j = 0; j < 8; ++j) { vh[j] = bh[i * 8 + j]; vl[j] = bl[i * 8 + j]; }
    *(half8*)(Bh + (size_t)k * 64 + i * 8) = vh;
    *(half8*)(Bl + (size_t)k * 64 + i * 8) = vl;
  }
  __syncthreads();
  if (threadIdx.x < DIM) {
    atomicMax((unsigned*)&M1[threadIdx.x], lm1[threadIdx.x]);
    atomicMax((unsigned*)&M2[threadIdx.x], lm2[threadIdx.x]);
  }
}

__global__ __launch_bounds__(256) void aprep_kernel(const float* __restrict__ z,
                                                    const float* __restrict__ M1,
                                                    const float* __restrict__ M2,
                                                    float* __restrict__ P,
                                                    float* __restrict__ Q,
                                                    _Float16* __restrict__ Ah,
                                                    _Float16* __restrict__ Al,
                                                    float* __restrict__ Bn) {
  const int row = blockIdx.x * 256 + threadIdx.x;
  const int t = row >> 3, c = row & 7;
  _Float16 ah[64], al[64];
  float S = 0.0f;
#pragma unroll
  for (int d = 0; d < DIM; ++d) {
    float mu = z[t * 512 + d * 8 + c];
    float lv = z[t * 512 + 256 + d * 8 + c];
    lv = fminf(fmaxf(lv, -30.0f), 20.0f);
    float stdv = expf(0.5f * lv);
    float iv = 1.0f / (stdv * stdv);          // identical to R2 expression
    float p = mu * iv;
    float q = 0.5f * (1.0f - iv);
    P[row * DIM + d] = p;
    Q[row * DIM + d] = q;
    S += fabsf(p) * M1[d] + fabsf(q) * M2[d];
    _Float16 ph = (_Float16)p;
    _Float16 qh = (_Float16)q;
    ah[d] = ph;       al[d] = (_Float16)((p - (float)ph) * 2048.0f);
    ah[32 + d] = qh;  al[32 + d] = (_Float16)((q - (float)qh) * 2048.0f);
  }
#pragma unroll
  for (int i = 0; i < 8; ++i) {
    half8 vh, vl;
#pragma unroll
    for (int j = 0; j < 8; ++j) { vh[j] = ah[i * 8 + j]; vl[j] = al[i * 8 + j]; }
    *(half8*)(Ah + (size_t)row * 64 + i * 8) = vh;
    *(half8*)(Al + (size_t)row * 64 + i * 8) = vl;
  }
  Bn[row] = 2e-5f * S + 1e-3f;   // rigorous bound (analysis ~7e-6*S) + margin
}

__global__ __launch_bounds__(256, 4) void filter_kernel(const _Float16* __restrict__ Ah,
                                                        const _Float16* __restrict__ Al,
                                                        const _Float16* __restrict__ Bh,
                                                        const _Float16* __restrict__ Bl,
                                                        const float* __restrict__ Bn,
                                                        float* __restrict__ W1,
                                                        unsigned* __restrict__ I1) {
  const int lane = threadIdx.x & 63;
  const int wave = threadIdx.x >> 6;
  const int rowgroup = blockIdx.x >> 2;        // 0..255
  const int split = blockIdx.x & 3;            // 0..3
  const int rowbase = rowgroup * 64 + wave * 16;
  const int c16 = lane & 15, quad = lane >> 4;

  // A fragments: A[m=lane&15][k=quad*8+j], K=64 -> two frags per operand
  const size_t abase = (size_t)(rowbase + c16) * 64 + quad * 8;
  const half8 uh0 = *(const half8*)(Ah + abase);
  const half8 uh1 = *(const half8*)(Ah + abase + 32);
  const half8 ul0 = *(const half8*)(Al + abase);
  const half8 ul1 = *(const half8*)(Al + abase + 32);

  float a1[4], a2[4];
  unsigned i1[4];
#pragma unroll
  for (int r = 0; r < 4; ++r) { a1[r] = -INFINITY; a2[r] = -INFINITY; i1[r] = 0; }

  const int kbase = split * SPLITK;
#pragma unroll 1
  for (int t = 0; t < NTILES; ++t) {
    const int cb0 = kbase + t * 16;
    const size_t bbase = (size_t)(cb0 + c16) * 64 + quad * 8;
    const half8 vh0 = *(const half8*)(Bh + bbase);
    const half8 vh1 = *(const half8*)(Bh + bbase + 32);
    const half8 vl0 = *(const half8*)(Bl + bbase);
    const half8 vl1 = *(const half8*)(Bl + bbase + 32);

    f32x4 hh = {0.f, 0.f, 0.f, 0.f};
    hh = __builtin_amdgcn_mfma_f32_16x16x32_f16(uh0, vh0, hh, 0, 0, 0);
    hh = __builtin_amdgcn_mfma_f32_16x16x32_f16(uh1, vh1, hh, 0, 0, 0);
    f32x4 xl = {0.f, 0.f, 0.f, 0.f};
    xl = __builtin_amdgcn_mfma_f32_16x16x32_f16(ul0, vh0, xl, 0, 0, 0);
    xl = __builtin_amdgcn_mfma_f32_16x16x32_f16(ul1, vh1, xl, 0, 0, 0);
    xl = __builtin_amdgcn_mfma_f32_16x16x32_f16(uh0, vl0, xl, 0, 0, 0);
    xl = __builtin_amdgcn_mfma_f32_16x16x32_f16(uh1, vl1, xl, 0, 0, 0);

    const unsigned kcur = (unsigned)(cb0 + c16);
#pragma unroll
    for (int r = 0; r < 4; ++r) {
      const float v = hh[r] + xl[r] * (1.0f / 2048.0f);
      const bool gt = v > a1[r];
      a2[r] = fmaxf(a2[r], fminf(v, a1[r]));   // old a1
      a1[r] = fmaxf(a1[r], v);
      i1[r] = gt ? kcur : i1[r];
    }
  }
#pragma unroll
  for (int r = 0; r < 4; ++r) {
    const int row_r = rowbase + quad * 4 + r;  // C: row=(lane>>4)*4+reg
    const float twoB = 2.0f * Bn[row_r];
    const unsigned flag = (a2[r] >= a1[r] - twoB) ? 0x80000000u : 0u;
    W1[(size_t)row_r * 64 + split * 16 + c16] = a1[r];
    I1[(size_t)row_r * 64 + split * 16 + c16] = flag | i1[r];
  }
}

#define EXACT_SCORE(kk, out)                                             \
  {                                                                      \
    float s0 = 0.0f, s1 = 0.0f, s2 = 0.0f, s3 = 0.0f;                    \
    _Pragma("unroll")                                                    \
    for (int m = 0; m < 8; ++m) {                                        \
      const float4 cv = cb4[(kk) * 8 + m];                               \
      const int d = 4 * m;                                               \
      s0 = fmaf(cv.x, fmaf(q[d + 0], cv.x, p[d + 0]), s0);               \
      s1 = fmaf(cv.y, fmaf(q[d + 1], cv.y, p[d + 1]), s1);               \
      s2 = fmaf(cv.z, fmaf(q[d + 2], cv.z, p[d + 2]), s2);               \
      s3 = fmaf(cv.w, fmaf(q[d + 3], cv.w, p[d + 3]), s3);               \
    }                                                                    \
    out = (s0 + s1) + (s2 + s3);                                         \
  }

__global__ __launch_bounds__(256, 2) void merge_kernel(const float* __restrict__ P,
                                                       const float* __restrict__ Q,
                                                       const float* __restrict__ cb,
                                                       const float* __restrict__ W1,
                                                       const unsigned* __restrict__ I1,
                                                       int* __restrict__ idx_final,
                                                       float* __restrict__ out2,
                                                       const double* __restrict__ partials,
                                                       float* __restrict__ out1) {
  const int lane = threadIdx.x & 63;
  const int wave = threadIdx.x >> 6;
  const int row = blockIdx.x * 4 + wave;
  const int split = lane >> 4, c16 = lane & 15;

  float p[DIM], q[DIM];
#pragma unroll
  for (int d = 0; d < DIM; ++d) { p[d] = P[row * DIM + d]; q[d] = Q[row * DIM + d]; }
  const float4* __restrict__ cb4 = (const float4*)cb;

  const unsigned pi = I1[(size_t)row * 64 + lane];
  const bool flag = (pi >> 31) != 0u;
  const int i1 = (int)(pi & 0x7FFFFFFFu);

  float best;
  int bk;
  if (!flag) {
    EXACT_SCORE(i1, best);
    bk = i1;
  } else {
    best = -INFINITY; bk = 0;
#pragma unroll 1
    for (int t = 0; t < NTILES; ++t) {
      const int k = split * SPLITK + t * 16 + c16;
      float s;
      EXACT_SCORE(k, s);
      if (s > best) { best = s; bk = k; }      // ascending k: first-max
    }
  }
  // cross-lane argmax, min-k on ties
#pragma unroll
  for (int off = 1; off < 64; off <<= 1) {
    const float ov = __shfl_xor(best, off);
    const int ok = __shfl_xor(bk, off);
    if (ov > best || (ov == best && ok < bk)) { best = ov; bk = ok; }
  }
  if (lane == 0) { idx_final[row] = bk; out2[row] = (float)bk; }
  if (blockIdx.x == 0 && threadIdx.x == 0) {
    double s = 0.0;
    for (int i = 0; i < 256; ++i) s += partials[i];
    out1[0] = (float)(s * (1.4426 * 0.5) / (double)NROWS);
  }
}

__global__ __launch_bounds__(256) void gather_kernel(const float* __restrict__ cb,
                                                     const int* __restrict__ idx_final,
                                                     float* __restrict__ out0) {
  const int j = blockIdx.x * 256 + threadIdx.x;  // [0, 524288)
  const int t = j >> 8, r = j & 255;
  const int d = r >> 3, c = r & 7;
  const int n = t * 8 + c;
  out0[j] = cb[idx_final[n] * DIM + d];
}

extern "C" void kernel_launch(void* const* d_in, const int* in_sizes, int n_in,
                              void* d_out, int out_size, void* d_ws, size_t ws_size,
                              hipStream_t stream) {
  const float* z  = (const float*)d_in[0];
  const float* cb = (const float*)d_in[2];   // d_in[1]=noise unused (STE cancels)

  char* ws = (char*)d_ws;
  float*      M1 = (float*)(ws + WS_M1);
  float*      M2 = (float*)(ws + WS_M2);
  double* partials = (double*)(ws + WS_PART);
  float*      P  = (float*)(ws + WS_P);
  float*      Q  = (float*)(ws + WS_Q);
  float*      Bn = (float*)(ws + WS_BN);
  _Float16*   Ah = (_Float16*)(ws + WS_AH);
  _Float16*   Al = (_Float16*)(ws + WS_AL);
  _Float16*   Bh = (_Float16*)(ws + WS_BH);
  _Float16*   Bl = (_Float16*)(ws + WS_BL);
  float*      W1 = (float*)(ws + WS_W1);
  unsigned*   I1 = (unsigned*)(ws + WS_I1);
  int* idx_final = (int*)(ws + WS_IDX);

  float* out0 = (float*)d_out;            // 524288
  float* out1 = out0 + 524288;            // 1
  float* out2 = out1 + 1;                 // 16384

  hipMemsetAsync(ws + WS_M1, 0, 256, stream);                 // M1, M2 = 0
  cbprep_kernel<<<KSIZE / 256, 256, 0, stream>>>(cb, Bh, Bl, M1, M2);
  aprep_kernel<<<NROWS / 256, 256, 0, stream>>>(z, M1, M2, P, Q, Ah, Al, Bn);
  kl_kernel<<<256, 256, 0, stream>>>(z, partials);
  filter_kernel<<<1024, 256, 0, stream>>>(Ah, Al, Bh, Bl, Bn, W1, I1);
  merge_kernel<<<NROWS / 4, 256, 0, stream>>>(P, Q, cb, W1, I1,
                                              idx_final, out2, partials, out1);
  gather_kernel<<<(NTOK * 256) / 256, 256, 0, stream>>>(cb, idx_final, out0);
}

// Round 5
// 439.208 us; speedup vs baseline: 2.6649x; 2.6649x over previous
//
#include <hip/hip_runtime.h>
#include <math.h>

// ---------------------------------------------------------------------------
// GaussianQuant — MFMA-filtered argmax, R5 (R4 + compile fix).
// score[n,k] = sum_d p*c + q*c^2;  u=[p,q] (64), v=[c,c^2] (64), score=u.v
// fp16 hi/lo split (lo pre-scaled x2048):  s ~= uh.vh + (ul.vh + uh.vl)/2048
// Rigorous |err| <= B = 5e-6*S + 1e-4,  S = sum |p|M1 + |q|M2.
// Filter: per (row, c16, split) slice keep top1 idx + flag (top2 within 2B).
// Merge: exact fp32 rescore (bit-identical to the R2 formula that passed) of
// all 128 slice winners + whole-wave rescans of flagged slices.
// ---------------------------------------------------------------------------

typedef _Float16 half8 __attribute__((ext_vector_type(8)));
typedef float f32x4 __attribute__((ext_vector_type(4)));

#define DIM 32
#define NTOK 2048
#define NROWS 16384
#define KSIZE 16384
#define NSPLIT 8
#define SPLITK (KSIZE / NSPLIT)        // 2048
#define NTILES (SPLITK / 16)           // 128
#define NSLICE (NSPLIT * 16)           // 128 slices (winners) per row

// ws layout (bytes)
#define WS_M1   0                       // 32 float (memset 0)
#define WS_M2   128                     // 32 float
#define WS_PART 512                     // 256 double
#define WS_PQ   4096                    // 16384*64*4 = 4 MB  (p[32],q[32] per row)
#define WS_BN   (WS_PQ + 4194304)       // 64 KB
#define WS_AH   (WS_BN + 65536)         // 2 MB fp16
#define WS_AL   (WS_AH + 2097152)       // 2 MB
#define WS_BH   (WS_AL + 2097152)       // 2 MB
#define WS_BL   (WS_BH + 2097152)       // 2 MB
#define WS_I1   (WS_BL + 2097152)       // 16384*128*4 = 8 MB
#define WS_IDX  (WS_I1 + 8388608)       // 64 KB

__global__ __launch_bounds__(256) void kl_kernel(const float* __restrict__ z,
                                                 double* __restrict__ partials) {
  const int tid = threadIdx.x;
  const int lane = tid & 63;
  const int wave = tid >> 6;
  double s = 0.0;
  for (int j = blockIdx.x * 256 + tid; j < NTOK * 256; j += 256 * 256) {
    const int t = j >> 8, r = j & 255;
    float mu = z[t * 512 + r];
    float lv = z[t * 512 + 256 + r];
    lv = fminf(fmaxf(lv, -30.0f), 20.0f);
    float var = expf(lv);
    s += (double)(mu * mu + var - 1.0f - lv);
  }
  for (int off = 32; off > 0; off >>= 1) s += __shfl_down(s, off);
  __shared__ double wsum[4];
  if (lane == 0) wsum[wave] = s;
  __syncthreads();
  if (tid == 0) partials[blockIdx.x] = (wsum[0] + wsum[1]) + (wsum[2] + wsum[3]);
}

__global__ __launch_bounds__(256) void cbprep_kernel(const float* __restrict__ cb,
                                                     _Float16* __restrict__ Bh,
                                                     _Float16* __restrict__ Bl,
                                                     float* __restrict__ M1,
                                                     float* __restrict__ M2) {
  __shared__ unsigned lm1[DIM], lm2[DIM];
  if (threadIdx.x < DIM) { lm1[threadIdx.x] = 0u; lm2[threadIdx.x] = 0u; }
  __syncthreads();
  const int k = blockIdx.x * 256 + threadIdx.x;
  _Float16 bh[64], bl[64];
#pragma unroll
  for (int d = 0; d < DIM; ++d) {
    float c = cb[k * DIM + d];
    float c2 = c * c;
    _Float16 ch = (_Float16)c;
    _Float16 cl = (_Float16)((c - (float)ch) * 2048.0f);
    _Float16 sh = (_Float16)c2;
    _Float16 sl = (_Float16)((c2 - (float)sh) * 2048.0f);
    bh[d] = ch; bh[32 + d] = sh;
    bl[d] = cl; bl[32 + d] = sl;
    atomicMax(&lm1[d], __float_as_uint(fabsf(c)));
    atomicMax(&lm2[d], __float_as_uint(c2));
  }
#pragma unroll
  for (int i = 0; i < 8; ++i) {
    half8 vh, vl;
#pragma unroll
    for (int j = 0; j < 8; ++j) { vh[j] = bh[i * 8 + j]; vl[j] = bl[i * 8 + j]; }
    *(half8*)(Bh + (size_t)k * 64 + i * 8) = vh;
    *(half8*)(Bl + (size_t)k * 64 + i * 8) = vl;
  }
  __syncthreads();
  if (threadIdx.x < DIM) {
    atomicMax((unsigned*)&M1[threadIdx.x], lm1[threadIdx.x]);
    atomicMax((unsigned*)&M2[threadIdx.x], lm2[threadIdx.x]);
  }
}

__global__ __launch_bounds__(256) void aprep_kernel(const float* __restrict__ z,
                                                    const float* __restrict__ M1,
                                                    const float* __restrict__ M2,
                                                    float* __restrict__ PQ,
                                                    _Float16* __restrict__ Ah,
                                                    _Float16* __restrict__ Al,
                                                    float* __restrict__ Bn) {
  const int row = blockIdx.x * 256 + threadIdx.x;
  const int t = row >> 3, c = row & 7;
  _Float16 ah[64], al[64];
  float S = 0.0f;
#pragma unroll
  for (int d = 0; d < DIM; ++d) {
    float mu = z[t * 512 + d * 8 + c];
    float lv = z[t * 512 + 256 + d * 8 + c];
    lv = fminf(fmaxf(lv, -30.0f), 20.0f);
    float stdv = expf(0.5f * lv);
    float iv = 1.0f / (stdv * stdv);          // identical to R2 expression
    float p = mu * iv;
    float q = 0.5f * (1.0f - iv);
    PQ[(size_t)row * 64 + d] = p;
    PQ[(size_t)row * 64 + 32 + d] = q;
    S += fabsf(p) * M1[d] + fabsf(q) * M2[d];
    _Float16 ph = (_Float16)p;
    _Float16 qh = (_Float16)q;
    ah[d] = ph;       al[d] = (_Float16)((p - (float)ph) * 2048.0f);
    ah[32 + d] = qh;  al[32 + d] = (_Float16)((q - (float)qh) * 2048.0f);
  }
#pragma unroll
  for (int i = 0; i < 8; ++i) {
    half8 vh, vl;
#pragma unroll
    for (int j = 0; j < 8; ++j) { vh[j] = ah[i * 8 + j]; vl[j] = al[i * 8 + j]; }
    *(half8*)(Ah + (size_t)row * 64 + i * 8) = vh;
    *(half8*)(Al + (size_t)row * 64 + i * 8) = vl;
  }
  Bn[row] = 5e-6f * S + 1e-4f;   // rigorous: split err 4.8e-7*S + accum 3.9e-6*S
}

// grid (64, 8): x = rowgroup (256 rows), y = split. 4 waves x 64 rows each.
__global__ __launch_bounds__(256, 3) void filter_kernel(const _Float16* __restrict__ Ah,
                                                        const _Float16* __restrict__ Al,
                                                        const _Float16* __restrict__ Bh,
                                                        const _Float16* __restrict__ Bl,
                                                        const float* __restrict__ Bn,
                                                        unsigned* __restrict__ I1) {
  const int lane = threadIdx.x & 63;
  const int wave = threadIdx.x >> 6;
  const int split = blockIdx.y;
  const int rowbase = blockIdx.x * 256 + wave * 64;   // 4 rowtiles of 16
  const int c16 = lane & 15, quad = lane >> 4;

  half8 uh0[4], uh1[4], ul0[4], ul1[4];
#pragma unroll
  for (int rt = 0; rt < 4; ++rt) {
    const size_t abase = (size_t)(rowbase + rt * 16 + c16) * 64 + quad * 8;
    uh0[rt] = *(const half8*)(Ah + abase);
    uh1[rt] = *(const half8*)(Ah + abase + 32);
    ul0[rt] = *(const half8*)(Al + abase);
    ul1[rt] = *(const half8*)(Al + abase + 32);
  }

  float a1[4][4], a2[4][4];
  unsigned i1[4][4];
#pragma unroll
  for (int rt = 0; rt < 4; ++rt)
#pragma unroll
    for (int r = 0; r < 4; ++r) { a1[rt][r] = -INFINITY; a2[rt][r] = -INFINITY; i1[rt][r] = 0; }

  const int k0 = split * SPLITK;
#pragma unroll 1
  for (int t = 0; t < NTILES; ++t) {
    const int cb0 = k0 + t * 16;
    const size_t bbase = (size_t)(cb0 + c16) * 64 + quad * 8;
    const half8 vh0 = *(const half8*)(Bh + bbase);
    const half8 vh1 = *(const half8*)(Bh + bbase + 32);
    const half8 vl0 = *(const half8*)(Bl + bbase);
    const half8 vl1 = *(const half8*)(Bl + bbase + 32);
    const unsigned kcur = (unsigned)(cb0 + c16);

#pragma unroll
    for (int rt = 0; rt < 4; ++rt) {
      f32x4 hh = {0.f, 0.f, 0.f, 0.f};
      hh = __builtin_amdgcn_mfma_f32_16x16x32_f16(uh0[rt], vh0, hh, 0, 0, 0);
      hh = __builtin_amdgcn_mfma_f32_16x16x32_f16(uh1[rt], vh1, hh, 0, 0, 0);
      f32x4 xl = {0.f, 0.f, 0.f, 0.f};
      xl = __builtin_amdgcn_mfma_f32_16x16x32_f16(ul0[rt], vh0, xl, 0, 0, 0);
      xl = __builtin_amdgcn_mfma_f32_16x16x32_f16(ul1[rt], vh1, xl, 0, 0, 0);
      xl = __builtin_amdgcn_mfma_f32_16x16x32_f16(uh0[rt], vl0, xl, 0, 0, 0);
      xl = __builtin_amdgcn_mfma_f32_16x16x32_f16(uh1[rt], vl1, xl, 0, 0, 0);
#pragma unroll
      for (int r = 0; r < 4; ++r) {
        const float v = fmaf(xl[r], 1.0f / 2048.0f, hh[r]);
        a2[rt][r] = fmaxf(a2[rt][r], fminf(v, a1[rt][r]));     // new 2nd-best
        const bool gt = v > a1[rt][r];
        a1[rt][r] = fmaxf(a1[rt][r], v);
        i1[rt][r] = gt ? kcur : i1[rt][r];
      }
    }
  }

#pragma unroll
  for (int rt = 0; rt < 4; ++rt)
#pragma unroll
    for (int r = 0; r < 4; ++r) {
      const int row_r = rowbase + rt * 16 + quad * 4 + r;  // C: row=(lane>>4)*4+reg
      const float twoB = 2.0f * Bn[row_r];
      const unsigned flag = (a2[rt][r] >= a1[rt][r] - twoB) ? 0x80000000u : 0u;
      I1[(size_t)row_r * NSLICE + split * 16 + c16] = flag | i1[rt][r];
    }
}

// exact fp32 score, p/q broadcast from LDS (no per-lane arrays -> no spills)
__device__ __forceinline__ float exact_score(const float4* __restrict__ cb4,
                                             const float4* __restrict__ spq,
                                             int k) {
  float s0 = 0.0f, s1 = 0.0f, s2 = 0.0f, s3 = 0.0f;
#pragma unroll
  for (int m = 0; m < 8; ++m) {
    const float4 cv = cb4[k * 8 + m];
    const float4 pv = spq[m];        // p[4m..4m+3]
    const float4 qv = spq[8 + m];    // q[4m..4m+3]
    s0 = fmaf(cv.x, fmaf(qv.x, cv.x, pv.x), s0);
    s1 = fmaf(cv.y, fmaf(qv.y, cv.y, pv.y), s1);
    s2 = fmaf(cv.z, fmaf(qv.z, cv.z, pv.z), s2);
    s3 = fmaf(cv.w, fmaf(qv.w, cv.w, pv.w), s3);
  }
  return (s0 + s1) + (s2 + s3);
}

// 1 wave per row; 4 rows per block.
__global__ __launch_bounds__(256, 4) void merge_kernel(const float* __restrict__ PQ,
                                                       const float* __restrict__ cb,
                                                       const unsigned* __restrict__ I1,
                                                       int* __restrict__ idx_final,
                                                       float* __restrict__ out2,
                                                       const double* __restrict__ partials,
                                                       float* __restrict__ out1) {
  __shared__ float4 spq_s[4][16];
  const int lane = threadIdx.x & 63;
  const int wave = threadIdx.x >> 6;
  const int row = blockIdx.x * 4 + wave;

  if (lane < 16)
    spq_s[wave][lane] = ((const float4*)(PQ + (size_t)row * 64))[lane];
  __syncthreads();
  const float4* spq = spq_s[wave];
  const float4* __restrict__ cb4 = (const float4*)cb;

  // phase A: exact-rescore the 128 slice winners (2 per lane)
  const unsigned e0 = I1[(size_t)row * NSLICE + lane];
  const unsigned e1 = I1[(size_t)row * NSLICE + 64 + lane];
  int bk = (int)(e0 & 0x7FFFFFFFu);
  float best = exact_score(cb4, spq, bk);
  {
    const int k1 = (int)(e1 & 0x7FFFFFFFu);
    const float s1v = exact_score(cb4, spq, k1);
    if (s1v > best || (s1v == best && k1 < bk)) { best = s1v; bk = k1; }
  }

  // phase B: whole-wave rescans of flagged slices
  unsigned long long m0 = __ballot((e0 >> 31) != 0u);
  unsigned long long m1 = __ballot((e1 >> 31) != 0u);
#pragma unroll 1
  for (int half = 0; half < 2; ++half) {
    unsigned long long m = half ? m1 : m0;
    while (m) {
      const int e = (half ? 64 : 0) + __builtin_ctzll(m);
      m &= m - 1;
      const int split = e >> 4, c16 = e & 15;
      const int ka = split * SPLITK + lane * 16 + c16;
      const int kb = ka + 64 * 16;
      const float sa = exact_score(cb4, spq, ka);
      const float sb = exact_score(cb4, spq, kb);
      if (sa > best || (sa == best && ka < bk)) { best = sa; bk = ka; }
      if (sb > best || (sb == best && kb < bk)) { best = sb; bk = kb; }
    }
  }

  // cross-lane argmax, min-k on ties (numpy first-max)
#pragma unroll
  for (int off = 1; off < 64; off <<= 1) {
    const float ov = __shfl_xor(best, off);
    const int ok = __shfl_xor(bk, off);
    if (ov > best || (ov == best && ok < bk)) { best = ov; bk = ok; }
  }
  if (lane == 0) { idx_final[row] = bk; out2[row] = (float)bk; }
  if (blockIdx.x == 0 && threadIdx.x == 0) {
    double s = 0.0;
    for (int i = 0; i < 256; ++i) s += partials[i];
    out1[0] = (float)(s * (1.4426 * 0.5) / (double)NROWS);
  }
}

__global__ __launch_bounds__(256) void gather_kernel(const float* __restrict__ cb,
                                                     const int* __restrict__ idx_final,
                                                     float* __restrict__ out0) {
  const int j = blockIdx.x * 256 + threadIdx.x;  // [0, 524288)
  const int t = j >> 8, r = j & 255;
  const int d = r >> 3, c = r & 7;
  const int n = t * 8 + c;
  out0[j] = cb[idx_final[n] * DIM + d];
}

extern "C" void kernel_launch(void* const* d_in, const int* in_sizes, int n_in,
                              void* d_out, int out_size, void* d_ws, size_t ws_size,
                              hipStream_t stream) {
  const float* z  = (const float*)d_in[0];
  const float* cb = (const float*)d_in[2];   // d_in[1]=noise unused (STE cancels)

  char* ws = (char*)d_ws;
  float*      M1 = (float*)(ws + WS_M1);
  float*      M2 = (float*)(ws + WS_M2);
  double* partials = (double*)(ws + WS_PART);
  float*      PQ = (float*)(ws + WS_PQ);
  float*      Bn = (float*)(ws + WS_BN);
  _Float16*   Ah = (_Float16*)(ws + WS_AH);
  _Float16*   Al = (_Float16*)(ws + WS_AL);
  _Float16*   Bh = (_Float16*)(ws + WS_BH);
  _Float16*   Bl = (_Float16*)(ws + WS_BL);
  unsigned*   I1 = (unsigned*)(ws + WS_I1);
  int* idx_final = (int*)(ws + WS_IDX);

  float* out0 = (float*)d_out;            // 524288
  float* out1 = out0 + 524288;            // 1
  float* out2 = out1 + 1;                 // 16384

  (void)hipMemsetAsync(ws + WS_M1, 0, 256, stream);           // M1, M2 = 0
  cbprep_kernel<<<KSIZE / 256, 256, 0, stream>>>(cb, Bh, Bl, M1, M2);
  aprep_kernel<<<NROWS / 256, 256, 0, stream>>>(z, M1, M2, PQ, Ah, Al, Bn);
  kl_kernel<<<256, 256, 0, stream>>>(z, partials);
  dim3 fgrid(64, NSPLIT);
  filter_kernel<<<fgrid, 256, 0, stream>>>(Ah, Al, Bh, Bl, Bn, I1);
  merge_kernel<<<NROWS / 4, 256, 0, stream>>>(PQ, cb, I1, idx_final, out2,
                                              partials, out1);
  gather_kernel<<<(NTOK * 256) / 256, 256, 0, stream>>>(cb, idx_final, out0);
}